// Round 9
// baseline (215.732 us; speedup 1.0000x reference)
//
#include <hip/hip_runtime.h>
#include <math.h>

// Problem constants: B=16, H=W=128, C=64, M1=M2=16
// Workspace layout (float offsets):
#define OFF_TBL 0u            // 128 x {cos,sin}(2*pi*m/128)          (256)
#define OFF_S1  256u          // instance-norm-1 raw sums [b*64+c][2] (2048)
#define OFF_S2  2304u         // instance-norm-2 stats (s1,s2)        (2048)
#define OFF_PQ  4352u         // PT[b][(ky*64+c)*2+ri][h] u32-packed bf16 hi/lo (4194304)
                              //   aliased later with Q[b][h][ky][o][2] f32
#define OFF_X   4198656u      // X[b][kx][ky][c][2] f32               (1048576)
#define OFF_O   5247232u      // Out[b][kx][ky][o][2] f32             (1048576)
                              //   head doubles (pre-mix) as u16 trig tables:
                              //   FdAh[32][128] @0, FdAl @4096, EdAh[64][128] @8192, EdAl @16384
#define OFF_WT  6295808u      // WT[mode][i][o][2]                    (4194304)
// total = 10490112 floats = 41.96 MB
// X region is dead after k_mix -> reuse as u16 arrays for bf16-split MLP weights:
//   u16[0..8192) w1hi   [8192..16384) w1lo   [16384..24576) w2hi
//   [24576..32768) w2lo  [32768..36864) Mhi  [36864..40960) Mlo

typedef __attribute__((ext_vector_type(8))) short bfrag;
typedef __attribute__((ext_vector_type(4))) float f4v;
#define MFMA(A,B,C) __builtin_amdgcn_mfma_f32_16x16x32_bf16(A,B,C,0,0,0)

__device__ __forceinline__ unsigned short f2bf_rn(float x) {
    unsigned u = __float_as_uint(x);
    unsigned r = u + 0x7FFFu + ((u >> 16) & 1u);
    return (unsigned short)(r >> 16);
}
__device__ __forceinline__ float bf2f(unsigned short h) {
    return __uint_as_float(((unsigned)h) << 16);
}
__device__ __forceinline__ void split2(float x, unsigned short& hi, unsigned short& lo) {
    hi = f2bf_rn(x);
    lo = f2bf_rn(x - bf2f(hi));
}
// tanh-form GELU; matches exact GELU to <1e-5 for |x| <= 0.5 (our range)
__device__ __forceinline__ float gelu_t(float x) {
    float u = 0.79788456080286536f * (x + 0.044715f * x * x * x);
    float e = __expf(2.f * u);
    float th = 1.f - 2.f / (e + 1.f);
    return 0.5f * x * (1.f + th);
}

// block 0: twiddle table + zero S1/S2. blocks 1..48: bf16-split trig tables
// (F for dftw, E for dfth) into the O region (dead until k_mix overwrites).
__global__ void k_init(float* __restrict__ ws) {
    int t = threadIdx.x, bid = blockIdx.x;
    if (bid == 0) {
        if (t < 128) {
            double ang = 6.283185307179586476925286766559 * (double)t / 128.0;
            ws[OFF_TBL + 2*t]     = (float)cos(ang);
            ws[OFF_TBL + 2*t + 1] = (float)sin(ang);
        }
        for (int i = t; i < 4096; i += 256) ws[OFF_S1 + i] = 0.f;
        return;
    }
    int e = (bid - 1)*256 + t;   // 0..12287
    unsigned short* OU = (unsigned short*)(ws + OFF_O);
    const double TWO_PI = 6.283185307179586476925286766559;
    if (e < 4096) {              // FdA[row=ri*16+ky][w]: re rows cos, im rows -sin
        int row = e >> 7, w = e & 127, ky = row & 15;
        double ang = TWO_PI * (double)((ky * w) & 127) / 128.0;
        double v = (row < 16) ? cos(ang) : -sin(ang);
        unsigned short hi, lo; split2((float)v, hi, lo);
        OU[e] = hi; OU[4096 + e] = lo;
    } else {                     // EdA[row=2kx+s][h]: s=0 cos, s=1 sin (of freq f(kx))
        int e2 = e - 4096, row = e2 >> 7, h = e2 & 127;
        int kx = row >> 1, f = kx < 16 ? kx : 96 + kx;
        double ang = TWO_PI * (double)((f * h) & 127) / 128.0;
        double v = (row & 1) ? sin(ang) : cos(ang);
        unsigned short hi, lo; split2((float)v, hi, lo);
        OU[8192 + e2] = hi; OU[16384 + e2] = lo;
    }
}

// weight transpose: [i][o][kx][ky] (x4 arrays) -> WT[mode][i][o][{re,im}]. grid (64=i, 2=part)
__global__ void k_trans(const float* __restrict__ w1r, const float* __restrict__ w1i,
                        const float* __restrict__ w2r, const float* __restrict__ w2i,
                        float* __restrict__ ws) {
    __shared__ float Lr[16*257], Li[16*257];
    int t = threadIdx.x;
    int i = blockIdx.x;
    int part = blockIdx.y;
    float* WT = ws + OFF_WT;
    const float* wr = part ? w2r : w1r;
    const float* wi = part ? w2i : w1i;
    for (int oc = 0; oc < 4; oc++) {
        int o0 = oc * 16;
        __syncthreads();
        for (int idx = t; idx < 4096; idx += 256) {
            int oo = idx >> 8, m = idx & 255;
            Lr[oo*257 + m] = wr[(i*64 + o0 + oo)*256 + m];
            Li[oo*257 + m] = wi[(i*64 + o0 + oo)*256 + m];
        }
        __syncthreads();
        for (int idx = t; idx < 8192; idx += 256) {
            int mode = idx >> 5, rem = idx & 31, oo = rem >> 1, ri = rem & 1;
            float val = ri ? Li[oo*257 + mode] : Lr[oo*257 + mode];
            int gm = part*256 + mode;
            WT[((gm*64 + i)*64 + (o0 + oo))*2 + ri] = val;
        }
    }
}

// bf16-split MLP weights + iDFT-w matrix M into the dead X region. grid 80
__global__ void k_wmlp(const float* __restrict__ mw1, const float* __restrict__ mw2,
                       float* __restrict__ ws) {
    int i = blockIdx.x * 256 + threadIdx.x;   // [0, 20480)
    unsigned short* xu = (unsigned short*)(ws + OFF_X);
    if (i < 8192) {
        unsigned short hi, lo; split2(mw1[i], hi, lo);
        xu[i] = hi; xu[8192 + i] = lo;
    } else if (i < 16384) {
        int k = i - 8192;
        unsigned short hi, lo; split2(mw2[k], hi, lo);
        xu[16384 + k] = hi; xu[24576 + k] = lo;
    } else if (i < 20480) {
        int m = i - 16384;           // w*32 + k
        int w = m >> 5, k = m & 31;
        int ky = k >> 1;
        double ang = 6.283185307179586476925286766559 * (double)((ky * w) & 127) / 128.0;
        double v = (k & 1) ? -sin(ang) : cos(ang);
        double a = (ky == 0) ? 1.0 : 2.0;
        float val = (float)(v * a) * (1.f/16384.f);
        unsigned short hi, lo; split2(val, hi, lo);
        xu[32768 + m] = hi; xu[36864 + m] = lo;
    }
}

// MFMA forward DFT along w on RAW x, sector-dense reads, c split across 2 blocks
// for occupancy (grid 1024 = 4 blocks/CU). grid (hq=32, cs=2, b=16): block =
// 4 h (wave wv owns h = hq*4+wv) x 32 c (c0 = cs*32). Instance-norm-1 stats
// folded into staging. Wave-private staging; barrier only before PT write.
// Output PT[b][(ky*64+c)*2+ri][h] u32-packed bf16 hi/lo (layout unchanged).
__global__ __launch_bounds__(256) void k_dftw(const float* __restrict__ x, float* __restrict__ ws) {
    __shared__ unsigned BTall[4096];    // 16KB: per-wave 4KB {BTh 2KB | BTl 2KB}; reused as trans
    int t = threadIdx.x;
    int hq = blockIdx.x, cs = blockIdx.y, b = blockIdx.z;
    int c0 = cs*32;
    int l = t & 63, wv = t >> 6;
    int h = hq*4 + wv;
    char* wbase = (char*)BTall + wv*4096;

    const unsigned short* OU = (const unsigned short*)(ws + OFF_O);
    const unsigned short* FdAh = OU, *FdAl = OU + 4096;

    // A-frags: FdA rows (mt*16 + lane&15), k = kc*32 + oct*8
    bfrag ma_h[2][4], ma_l[2][4];
    #pragma unroll
    for (int mt = 0; mt < 2; mt++)
        #pragma unroll
        for (int kc = 0; kc < 4; kc++) {
            int off = (mt*16 + (l & 15))*128 + kc*32 + (l >> 4)*8;
            ma_h[mt][kc] = *(const bfrag*)(FdAh + off);
            ma_l[mt][kc] = *(const bfrag*)(FdAl + off);
        }
    f4v acc[2][2];
    #pragma unroll
    for (int mt = 0; mt < 2; mt++)
        #pragma unroll
        for (int nt = 0; nt < 2; nt++) acc[mt][nt] = (f4v){0.f,0.f,0.f,0.f};

    float s1a[4] = {0,0,0,0}, s2a[4] = {0,0,0,0};   // stats for c = c0 + 4*cq + j
    int cq = l & 7, r = l >> 3;
    const float* xb = x + ((long)(b*128 + h))*8192 + c0;  // this wave's h row, c half

    #pragma unroll
    for (int kc = 0; kc < 4; kc++) {
        // ---- stage (dense): 8-lane groups read 128B contiguous (2 full sectors) ----
        #pragma unroll
        for (int it = 0; it < 2; it++) {
            int wp = it*8 + r;                       // w-pair 0..15
            const float* src = xb + (kc*32 + wp*2)*64 + cq*4;
            float4 a = *(const float4*)src;
            float4 bb = *(const float4*)(src + 64);
            #pragma unroll
            for (int j = 0; j < 4; j++) {
                float va = ((const float*)&a)[j], vb = ((const float*)&bb)[j];
                s1a[j] += va + vb;
                s2a[j] += va*va + vb*vb;
                unsigned short ah, al2, bh2, bl2;
                split2(va, ah, al2); split2(vb, bh2, bl2);
                unsigned hp = (unsigned)ah | ((unsigned)bh2 << 16);
                unsigned lp = (unsigned)al2 | ((unsigned)bl2 << 16);
                int lc = cq + 8*j;                   // col index 0..31
                unsigned bad = (unsigned)(lc*64 + ((wp*4) ^ (((lc >> 1) & 3) << 4)));
                *(unsigned*)(wbase + bad) = hp;
                *(unsigned*)(wbase + 2048 + bad) = lp;
            }
        }
        // ---- MFMA: 2 Ntiles x 2 Mtiles, 3-term hi/lo ----
        #pragma unroll
        for (int nt = 0; nt < 2; nt++) {
            int lc = nt*16 + (l & 15);
            unsigned ro = (unsigned)(lc*64 + (((l >> 4)*16) ^ (((lc >> 1) & 3) << 4)));
            bfrag bh = *(const bfrag*)(wbase + ro);
            bfrag bl = *(const bfrag*)(wbase + 2048 + ro);
            #pragma unroll
            for (int mt = 0; mt < 2; mt++) {
                f4v a_ = acc[mt][nt];
                a_ = MFMA(ma_h[mt][kc], bh, a_);
                a_ = MFMA(ma_h[mt][kc], bl, a_);
                a_ = MFMA(ma_l[mt][kc], bh, a_);
                acc[mt][nt] = a_;
            }
        }
    }
    // ---- stats reduce (over r-groups sharing cq) + atomics ----
    #pragma unroll
    for (int j = 0; j < 4; j++) {
        s1a[j] += __shfl_down(s1a[j], 8, 64);
        s1a[j] += __shfl_down(s1a[j], 16, 64);
        s1a[j] += __shfl_down(s1a[j], 32, 64);
        s2a[j] += __shfl_down(s2a[j], 8, 64);
        s2a[j] += __shfl_down(s2a[j], 16, 64);
        s2a[j] += __shfl_down(s2a[j], 32, 64);
    }
    if (l < 8) {
        #pragma unroll
        for (int j = 0; j < 4; j++) {
            int c = c0 + 4*cq + j;
            atomicAdd(&ws[OFF_S1 + (b*64 + c)*2],     s1a[j]);
            atomicAdd(&ws[OFF_S1 + (b*64 + c)*2 + 1], s2a[j]);
        }
    }
    // ---- epilogue: split-pack -> wave trans buf [trow=ri*16+ky][c_local 32] u32 ----
    #pragma unroll
    for (int mt = 0; mt < 2; mt++)
        #pragma unroll
        for (int nt = 0; nt < 2; nt++)
            #pragma unroll
            for (int rr = 0; rr < 4; rr++) {
                float v = acc[mt][nt][rr];
                unsigned short hi, lo; split2(v, hi, lo);
                int trow = mt*16 + (l >> 4)*4 + rr;
                // invert staging col permutation: lc = nt*16+(l&15) -> c_local = (lc&7)*4 + (lc>>3)
                int c_local = (l & 7)*4 + nt*2 + ((l >> 3) & 1);
                unsigned ad = (unsigned)(trow*128 + ((c_local*4) ^ ((trow & 7) << 4)));
                *(unsigned*)(wbase + ad) = ((unsigned)hi << 16) | (unsigned)lo;
            }
    __syncthreads();
    // ---- cross-wave gather: uint4 = 4 h values -> PT row segment ----
    unsigned* PT = (unsigned*)(ws + OFF_PQ);
    #pragma unroll
    for (int s = 0; s < 4; s++) {
        int seg = s*256 + t;                 // 1024 (trow,c) pairs
        int trow = seg >> 5, c = seg & 31;
        unsigned ad = (unsigned)(trow*128 + ((c*4) ^ ((trow & 7) << 4)));
        uint4 vz;
        vz.x = *(const unsigned*)((const char*)BTall + ad);
        vz.y = *(const unsigned*)((const char*)BTall + 4096 + ad);
        vz.z = *(const unsigned*)((const char*)BTall + 8192 + ad);
        vz.w = *(const unsigned*)((const char*)BTall + 12288 + ad);
        int ri = trow >> 4, ky = trow & 15;
        long grow = ((long)(ky*64 + c0 + c))*2 + ri;
        *(uint4*)(PT + (((long)b*2048 + grow) << 7) + hq*4) = vz;
    }
}

// MFMA forward DFT along h: X[2kx+s][(c,ri)] = EdA @ PT (per ky,b).
// Complex combine: Xr = G[2kx][colr]+G[2kx+1][coli], Xi = G[2kx][coli]-G[2kx+1][colr]
// via shfl_xor(1). grid (ky=16, b=16); wave wv = Mtile wv. X stays f32 legacy layout.
__global__ __launch_bounds__(256) void k_dfth(float* __restrict__ ws) {
    __shared__ unsigned Bsh[16384];   // BTh 32KB (128 cols x 256B) | BTl 32KB
    int t = threadIdx.x;
    int ky = blockIdx.x, b = blockIdx.y;
    int l = t & 63, wv = t >> 6;
    char* bh_base = (char*)Bsh;
    char* bl_base = bh_base + 32768;
    const unsigned* PT = (const unsigned*)(ws + OFF_PQ);
    const unsigned short* OU = (const unsigned short*)(ws + OFF_O);
    const unsigned short* EdAh = OU + 8192, *EdAl = OU + 16384;

    // ---- stage PT rows (col n = c*2+ri of this ky) -> BT[n][128 kk] hi/lo ----
    {
        int n = t >> 1, hh = (t & 1)*64;
        const uint4* src = (const uint4*)(PT + ((long)b*2048 + ky*128 + n)*128 + hh);
        #pragma unroll
        for (int jj = 0; jj < 16; jj++) {
            uint4 v = src[jj];
            unsigned h01 = (v.x >> 16) | (v.y & 0xFFFF0000u);
            unsigned h23 = (v.z >> 16) | (v.w & 0xFFFF0000u);
            unsigned l01 = (v.x & 0xFFFFu) | (v.y << 16);
            unsigned l23 = (v.z & 0xFFFFu) | (v.w << 16);
            int kk = hh + jj*4;
            unsigned ad = (unsigned)(n*256 + ((kk*2) ^ ((n & 7) << 4)));
            *(uint2*)(bh_base + ad) = make_uint2(h01, h23);
            *(uint2*)(bl_base + ad) = make_uint2(l01, l23);
        }
    }
    // A-frags for this wave's Mtile
    bfrag ea_h[4], ea_l[4];
    #pragma unroll
    for (int kc = 0; kc < 4; kc++) {
        int off = (wv*16 + (l & 15))*128 + kc*32 + (l >> 4)*8;
        ea_h[kc] = *(const bfrag*)(EdAh + off);
        ea_l[kc] = *(const bfrag*)(EdAl + off);
    }
    __syncthreads();
    f4v acc[8];
    #pragma unroll
    for (int nt = 0; nt < 8; nt++) acc[nt] = (f4v){0.f,0.f,0.f,0.f};
    #pragma unroll
    for (int kc = 0; kc < 4; kc++)
        #pragma unroll
        for (int nt = 0; nt < 8; nt++) {
            int col = nt*16 + (l & 15);
            unsigned ro = (unsigned)(col*256 + ((kc*64 + (l >> 4)*16) ^ ((col & 7) << 4)));
            bfrag bh = *(const bfrag*)(bh_base + ro);
            bfrag bl = *(const bfrag*)(bl_base + ro);
            acc[nt] = MFMA(ea_h[kc], bh, acc[nt]);
            acc[nt] = MFMA(ea_h[kc], bl, acc[nt]);
            acc[nt] = MFMA(ea_l[kc], bh, acc[nt]);
        }
    // ---- epilogue: complex combine + store X (f32, legacy layout) ----
    float* X = ws + OFF_X;
    #pragma unroll
    for (int nt = 0; nt < 8; nt++)
        #pragma unroll
        for (int p = 0; p < 2; p++) {
            float s0 = acc[nt][2*p], s1 = acc[nt][2*p + 1];
            float partner = __shfl_xor(s1, 1, 64);
            float res = (l & 1) ? (s0 - partner) : (s0 + partner);
            int kx = wv*8 + (l >> 4)*2 + p;
            X[(((long)b*32 + kx)*16 + ky)*128 + nt*16 + (l & 15)] = res;
        }
}

// per-mode complex mix with rho1 scaling folded into X staging. grid 512 (=mode)
__global__ void k_mix(float* __restrict__ ws) {
    __shared__ float Wsh[8192];
    __shared__ float Xs[2048];
    __shared__ float rhoT[1024];
    int t = threadIdx.x;
    int mode = blockIdx.x;
    int kxI = mode >> 4, ky = mode & 15;
    const float* WT = ws + OFF_WT;
    const float* X = ws + OFF_X;
    float* O = ws + OFF_O;
    for (int i = t; i < 1024; i += 256) {
        float a = ws[OFF_S1 + 2*i], s = ws[OFF_S1 + 2*i + 1];
        float m = a * (1.f/16384.f);
        float v = s * (1.f/16384.f) - m*m;
        rhoT[i] = rsqrtf(v + 1e-5f);
    }
    for (int idx = t; idx < 8192; idx += 256) Wsh[idx] = WT[(long)mode*8192 + idx];
    __syncthreads();
    for (int idx = t; idx < 2048; idx += 256) {
        int b = idx >> 7, r = idx & 127;
        Xs[idx] = X[((b*32 + kxI)*16 + ky)*128 + r] * rhoT[b*64 + (r >> 1)];
    }
    __syncthreads();
    int o = t & 63, bg = t >> 6;
    float accr[4] = {0,0,0,0}, acci[4] = {0,0,0,0};
    for (int i = 0; i < 64; i++) {
        float wr = Wsh[(i*64 + o)*2], wi = Wsh[(i*64 + o)*2 + 1];
        #pragma unroll
        for (int j = 0; j < 4; j++) {
            float xr = Xs[(bg*4 + j)*128 + 2*i], xi = Xs[(bg*4 + j)*128 + 2*i + 1];
            accr[j] += xr*wr - xi*wi;
            acci[j] += xr*wi + xi*wr;
        }
    }
    #pragma unroll
    for (int j = 0; j < 4; j++) {
        int b = bg*4 + j;
        float2* dst = (float2*)(O + ((b*32 + kxI)*16 + ky)*128);
        dst[o] = make_float2(accr[j], acci[j]);
    }
}

// Parseval stats of y directly from O. grid (16=b, 4=gg), 256 thr.
__global__ void k_pstats(float* __restrict__ ws) {
    __shared__ float red[256];
    int t = threadIdx.x, b = blockIdx.x, gg = blockIdx.y;
    int c = t & 63, g = t >> 6;
    const float* O = ws + OFF_O + (long)b*65536;   // [(kxI*16+ky)*128 + 2c]
    float t0 = 0.f, t2 = 0.f;
    int k0 = gg*8 + g*2;
    for (int kxI = k0; kxI < k0 + 2; kxI++)
        for (int ky = 0; ky < 16; ky++) {
            float re = O[(kxI*16 + ky)*128 + 2*c];
            float im = O[(kxI*16 + ky)*128 + 2*c + 1];
            float p = re*re + im*im;
            if (ky == 0) t0 += p; else t2 += p;
        }
    float s2p = 0.5f*t0 + 2.f*t2;
    if (gg == 0 && g == 0) {
        float ar = O[2*c], ai = O[2*c + 1];        // kxI=0, ky=0
        float t1 = ar*ar - ai*ai;
        for (int k = 1; k <= 15; k++) {
            float xr = O[(k*16)*128 + 2*c],        xi = O[(k*16)*128 + 2*c + 1];
            float yr = O[((32-k)*16)*128 + 2*c],   yi = O[((32-k)*16)*128 + 2*c + 1];
            t1 += 2.f*(xr*yr - xi*yi);
        }
        s2p += 0.5f*t1;
        ws[OFF_S2 + (b*64 + c)*2] = ar;            // s1 (mean term)
    }
    red[t] = s2p;
    __syncthreads();
    if (t < 64) {
        float s = red[t] + red[t+64] + red[t+128] + red[t+192];
        atomicAdd(&ws[OFF_S2 + (b*64 + t)*2 + 1], s * (1.f/16384.f));
    }
}

// inverse DFT along h: Q[b][h][ky][o] = sum_kx Out e^{+i 2pi f(kx) h/128}. grid (hg=16,b=16)
__global__ void k_idfth(float* __restrict__ ws) {
    __shared__ float Os[8192];
    __shared__ float tblL[256];
    int t = threadIdx.x;
    int hg = blockIdx.x, b = blockIdx.y;
    for (int i = t; i < 256; i += 256) tblL[i] = ws[OFF_TBL + i];
    const float* O = ws + OFF_O;
    float* Q = ws + OFF_PQ;
    int o = t & 63, kyg = t >> 6;
    float accr[4][8], acci[4][8];
    #pragma unroll
    for (int kk = 0; kk < 4; kk++)
        #pragma unroll
        for (int h = 0; h < 8; h++) { accr[kk][h] = 0.f; acci[kk][h] = 0.f; }
    for (int kc = 0; kc < 8; kc++) {
        __syncthreads();
        for (int idx = t; idx < 8192; idx += 256) Os[idx] = O[(long)b*65536 + kc*8192 + idx];
        __syncthreads();
        for (int k4 = 0; k4 < 4; k4++) {
            int kxI = kc*4 + k4;
            int freq = kxI < 16 ? kxI : 96 + kxI;
            float vr[4], vi[4];
            #pragma unroll
            for (int kk = 0; kk < 4; kk++) {
                int ky = kyg*4 + kk;
                vr[kk] = Os[((k4*16 + ky)*64 + o)*2];
                vi[kk] = Os[((k4*16 + ky)*64 + o)*2 + 1];
            }
            for (int h = 0; h < 8; h++) {
                int habs = hg*8 + h;
                int m = (freq * habs) & 127;
                float cs = tblL[2*m], sn = tblL[2*m + 1];
                #pragma unroll
                for (int kk = 0; kk < 4; kk++) {
                    accr[kk][h] += vr[kk]*cs - vi[kk]*sn;   // * e^{+i th}
                    acci[kk][h] += vr[kk]*sn + vi[kk]*cs;
                }
            }
        }
    }
    #pragma unroll
    for (int kk = 0; kk < 4; kk++)
        #pragma unroll
        for (int h = 0; h < 8; h++) {
            int ky = kyg*4 + kk, habs = hg*8 + h;
            float2* dst = (float2*)(Q + ((long)(b*128 + habs)*16 + ky)*128);
            dst[o] = make_float2(accr[kk][h], acci[kk][h]);
        }
}

// fused MFMA kernel: Y = M@Qm (iDFT-w), z = (Y-mu)*rho, h = GELU(z@W1+b1),
// out = h@W2+b2. G1 keeps hi/lo 3-MFMA (rho ~316 amplifies); z/W1/W2/h single bf16.
// LDS 75.3KB -> 2 blocks/CU. grid (h=128,b=16)
__global__ __launch_bounds__(256, 2) void k_mlp(const float* __restrict__ mb1,
                      const float* __restrict__ mb2,
                      float* __restrict__ out, const float* __restrict__ ws) {
    __shared__ unsigned short zhS[8192];                // z[w][64c], swz (w&7)<<4
    __shared__ unsigned short w1hS[8192];               // w1[j][64c], swz (j&7)<<4
    __shared__ unsigned short w2hS[8192];               // w2[o][128j], swz (o&15)<<4
    __shared__ unsigned short hhS[8192];                // h-half [w][64jl], swz (w&7)<<4
    __shared__ unsigned short qhS[2560], qlS[2560];     // QmT[c][40k] hi/lo
    __shared__ float muL[64], rhoL[64], b1L[128], b2L[64];
    int t = threadIdx.x;
    int h = blockIdx.x, b = blockIdx.y;
    int l = t & 63, wv = t >> 6;

    const unsigned short* xu = (const unsigned short*)(ws + OFF_X);
    const unsigned short* w1hG = xu;
    const unsigned short* w2hG = xu + 16384;
    const unsigned short* MhG  = xu + 32768, *MlG  = xu + 36864;

    // ---- stage weights into LDS (XOR swizzle), hi parts only ----
    for (int ch = t; ch < 1024; ch += 256) {       // w1: rows j, stride 128B
        int j = ch >> 3, c0 = (ch & 7) * 8;
        unsigned off = (unsigned)(j*128 + c0*2) ^ (unsigned)((j & 7) << 4);
        *(bfrag*)((char*)w1hS + off) = *(const bfrag*)(w1hG + ch*8);
    }
    for (int ch = t; ch < 1024; ch += 256) {       // w2: rows o, stride 256B
        int o = ch >> 4, j0 = (ch & 15) * 8;
        unsigned off = (unsigned)(o*256 + j0*2) ^ (unsigned)((o & 15) << 4);
        *(bfrag*)((char*)w2hS + off) = *(const bfrag*)(w2hG + ch*8);
    }
    // ---- QmT[c][k] build; lane-consecutive k -> ~2-way banks ----
    const float* Qp = ws + OFF_PQ + (long)(b*128 + h)*2048;
    for (int i = t; i < 2048; i += 256) {
        int k = i & 31, c = i >> 5;
        float v = Qp[(k >> 1)*128 + c*2 + (k & 1)];
        unsigned short hi, lo; split2(v, hi, lo);
        qhS[c*40 + k] = hi; qlS[c*40 + k] = lo;
    }
    if (t < 64) {
        float s1 = ws[OFF_S2 + (b*64+t)*2], s2 = ws[OFF_S2 + (b*64+t)*2 + 1];
        float m = s1 * (1.f/16384.f);
        float v = s2 * (1.f/16384.f) - m*m;
        muL[t] = m; rhoL[t] = rsqrtf(v + 1e-5f);
        b2L[t] = mb2[t];
    }
    if (t >= 64 && t < 192) b1L[t - 64] = mb1[t - 64];
    // M A-frags from global (rows w of this wave's two 16-row tiles)
    bfrag ma_h[2], ma_l[2];
    #pragma unroll
    for (int q = 0; q < 2; q++) {
        int w = (wv + 4*q)*16 + (l & 15);
        ma_h[q] = *(const bfrag*)(MhG + w*32 + (l >> 4)*8);
        ma_l[q] = *(const bfrag*)(MlG + w*32 + (l >> 4)*8);
    }
    __syncthreads();

    // ---- G1: Y = M @ Qm ; z = (Y - mu) * rho -> zhS (single bf16) ----
    #pragma unroll
    for (int q = 0; q < 2; q++) {
        int wt = wv + 4*q;
        #pragma unroll
        for (int ct = 0; ct < 4; ct++) {
            unsigned ro = (unsigned)((ct*16 + (l & 15))*80 + (l >> 4)*16);
            bfrag bh = *(const bfrag*)((const char*)qhS + ro);
            bfrag bl = *(const bfrag*)((const char*)qlS + ro);
            f4v acc = {0.f, 0.f, 0.f, 0.f};
            acc = MFMA(ma_h[q], bh, acc);
            acc = MFMA(ma_h[q], bl, acc);
            acc = MFMA(ma_l[q], bh, acc);
            int c = ct*16 + (l & 15);
            float mu_ = muL[c], rh_ = rhoL[c];
            #pragma unroll
            for (int r = 0; r < 4; r++) {
                int w = wt*16 + (l >> 4)*4 + r;
                float z = (acc[r] - mu_) * rh_;
                unsigned off = (unsigned)(w*128 + c*2) ^ (unsigned)((w & 7) << 4);
                *(unsigned short*)((char*)zhS + off) = f2bf_rn(z);
            }
        }
    }
    __syncthreads();

    // cache z A-frags (single, reused for both j-halves)
    bfrag za[2][2];
    #pragma unroll
    for (int q = 0; q < 2; q++) {
        int w = (wv + 4*q)*16 + (l & 15);
        #pragma unroll
        for (int ks = 0; ks < 2; ks++) {
            unsigned off = (unsigned)(w*128 + (ks*32 + (l >> 4)*8)*2) ^ (unsigned)((w & 7) << 4);
            za[q][ks] = *(const bfrag*)((const char*)zhS + off);
        }
    }
    f4v accO[2][4];
    #pragma unroll
    for (int q = 0; q < 2; q++)
        #pragma unroll
        for (int ot = 0; ot < 4; ot++) accO[q][ot] = (f4v){0.f,0.f,0.f,0.f};

    #pragma unroll
    for (int jh = 0; jh < 2; jh++) {
        // ---- G2: h-half = GELU(z @ W1[:, jh*64 .. +64) + b1) ----
        #pragma unroll
        for (int q = 0; q < 2; q++) {
            int wt = wv + 4*q;
            #pragma unroll
            for (int jt = 0; jt < 4; jt++) {
                int j = jh*64 + jt*16 + (l & 15);
                f4v acc = {0.f, 0.f, 0.f, 0.f};
                #pragma unroll
                for (int ks = 0; ks < 2; ks++) {
                    unsigned off = (unsigned)(j*128 + (ks*32 + (l >> 4)*8)*2) ^ (unsigned)((j & 7) << 4);
                    bfrag bh = *(const bfrag*)((const char*)w1hS + off);
                    acc = MFMA(za[q][ks], bh, acc);
                }
                float bj = b1L[j];
                #pragma unroll
                for (int r = 0; r < 4; r++) {
                    int w = wt*16 + (l >> 4)*4 + r;
                    float hv = gelu_t(acc[r] + bj);
                    int jl = jt*16 + (l & 15);
                    unsigned off = (unsigned)(w*128 + jl*2) ^ (unsigned)((w & 7) << 4);
                    *(unsigned short*)((char*)hhS + off) = f2bf_rn(hv);
                }
            }
        }
        __syncthreads();
        // ---- G3 partial: out += h-half @ W2[jh*64.., :] ----
        #pragma unroll
        for (int q = 0; q < 2; q++) {
            int w = (wv + 4*q)*16 + (l & 15);
            bfrag ha[2];
            #pragma unroll
            for (int ks = 0; ks < 2; ks++) {
                unsigned off = (unsigned)(w*128 + (ks*32 + (l >> 4)*8)*2) ^ (unsigned)((w & 7) << 4);
                ha[ks] = *(const bfrag*)((const char*)hhS + off);
            }
            #pragma unroll
            for (int ot = 0; ot < 4; ot++) {
                int o = ot*16 + (l & 15);
                f4v acc = accO[q][ot];
                #pragma unroll
                for (int ks = 0; ks < 2; ks++) {
                    int jj = jh*64 + ks*32 + (l >> 4)*8;
                    unsigned off = (unsigned)(o*256 + jj*2) ^ (unsigned)((o & 15) << 4);
                    bfrag bh = *(const bfrag*)((const char*)w2hS + off);
                    acc = MFMA(ha[ks], bh, acc);
                }
                accO[q][ot] = acc;
            }
        }
        __syncthreads();   // protect h buffer before next half overwrites
    }
    // ---- store out + b2 ----
    #pragma unroll
    for (int q = 0; q < 2; q++) {
        int wt = wv + 4*q;
        #pragma unroll
        for (int ot = 0; ot < 4; ot++) {
            int o = ot*16 + (l & 15);
            float bo = b2L[o];
            #pragma unroll
            for (int r = 0; r < 4; r++) {
                int w = wt*16 + (l >> 4)*4 + r;
                out[((long)(b*128 + h)*128 + w)*64 + o] = accO[q][ot][r] + bo;
            }
        }
    }
}

extern "C" void kernel_launch(void* const* d_in, const int* in_sizes, int n_in,
                              void* d_out, int out_size, void* d_ws, size_t ws_size,
                              hipStream_t stream) {
    const float* x   = (const float*)d_in[0];
    const float* w1r = (const float*)d_in[1];
    const float* w1i = (const float*)d_in[2];
    const float* w2r = (const float*)d_in[3];
    const float* w2i = (const float*)d_in[4];
    const float* mw1 = (const float*)d_in[5];
    const float* mb1 = (const float*)d_in[6];
    const float* mw2 = (const float*)d_in[7];
    const float* mb2 = (const float*)d_in[8];
    float* ws  = (float*)d_ws;
    float* out = (float*)d_out;

    k_init  <<<dim3(49),      dim3(256), 0, stream>>>(ws);
    k_trans <<<dim3(64,2),    dim3(256), 0, stream>>>(w1r, w1i, w2r, w2i, ws);
    k_dftw  <<<dim3(32,2,16), dim3(256), 0, stream>>>(x, ws);   // stats1 folded in
    k_dfth  <<<dim3(16,16),   dim3(256), 0, stream>>>(ws);
    k_mix   <<<dim3(512),     dim3(256), 0, stream>>>(ws);
    k_wmlp  <<<dim3(80),      dim3(256), 0, stream>>>(mw1, mw2, ws);  // X dead after k_mix
    k_pstats<<<dim3(16,4),    dim3(256), 0, stream>>>(ws);
    k_idfth <<<dim3(16,16),   dim3(256), 0, stream>>>(ws);
    k_mlp   <<<dim3(128,16),  dim3(256), 0, stream>>>(mb1, mb2, out, ws);
}

// Round 10
// 215.330 us; speedup vs baseline: 1.0019x; 1.0019x over previous
//
#include <hip/hip_runtime.h>
#include <math.h>

// Problem constants: B=16, H=W=128, C=64, M1=M2=16
// Workspace layout (float offsets):
#define OFF_TBL 0u            // 128 x {cos,sin}(2*pi*m/128)          (256)
#define OFF_S1  256u          // instance-norm-1 raw sums [b*64+c][2] (2048)
#define OFF_S2  2304u         // instance-norm-2 stats (s1,s2)        (2048)
#define OFF_PQ  4352u         // PT[b][(ky*64+c)*2+ri][h] u32-packed bf16 hi/lo (4194304)
                              //   aliased later with Q[b][h][ky][o][2] f32
#define OFF_X   4198656u      // X[b][kx][ky][c][2] f32               (1048576)
#define OFF_O   5247232u      // Out[b][kx][ky][o][2] f32             (1048576)
                              //   head doubles (pre-mix) as u16 trig tables:
                              //   FdAh[32][128] @0, FdAl @4096, EdAh[64][128] @8192, EdAl @16384
#define OFF_WT  6295808u      // WT[mode][i][o][2]                    (4194304)
// total = 10490112 floats = 41.96 MB
// X region is dead after k_mix -> reuse as u16 arrays for bf16-split MLP weights:
//   u16[0..8192) w1hi   [8192..16384) w1lo   [16384..24576) w2hi
//   [24576..32768) w2lo  [32768..36864) Mhi  [36864..40960) Mlo

typedef __attribute__((ext_vector_type(8))) short bfrag;
typedef __attribute__((ext_vector_type(4))) float f4v;
#define MFMA(A,B,C) __builtin_amdgcn_mfma_f32_16x16x32_bf16(A,B,C,0,0,0)

// compile-time float4 component select -- NO address-taken indexing (scratch hazard)
#define F4GET(v, i) ((i)==0 ? (v).x : (i)==1 ? (v).y : (i)==2 ? (v).z : (v).w)

__device__ __forceinline__ unsigned short f2bf_rn(float x) {
    unsigned u = __float_as_uint(x);
    unsigned r = u + 0x7FFFu + ((u >> 16) & 1u);
    return (unsigned short)(r >> 16);
}
__device__ __forceinline__ float bf2f(unsigned short h) {
    return __uint_as_float(((unsigned)h) << 16);
}
__device__ __forceinline__ void split2(float x, unsigned short& hi, unsigned short& lo) {
    hi = f2bf_rn(x);
    lo = f2bf_rn(x - bf2f(hi));
}
// tanh-form GELU; matches exact GELU to <1e-5 for |x| <= 0.5 (our range)
__device__ __forceinline__ float gelu_t(float x) {
    float u = 0.79788456080286536f * (x + 0.044715f * x * x * x);
    float e = __expf(2.f * u);
    float th = 1.f - 2.f / (e + 1.f);
    return 0.5f * x * (1.f + th);
}

// block 0: twiddle table + zero S1/S2. blocks 1..48: bf16-split trig tables
// (F for dftw, E for dfth) into the O region (dead until k_mix overwrites).
__global__ void k_init(float* __restrict__ ws) {
    int t = threadIdx.x, bid = blockIdx.x;
    if (bid == 0) {
        if (t < 128) {
            double ang = 6.283185307179586476925286766559 * (double)t / 128.0;
            ws[OFF_TBL + 2*t]     = (float)cos(ang);
            ws[OFF_TBL + 2*t + 1] = (float)sin(ang);
        }
        for (int i = t; i < 4096; i += 256) ws[OFF_S1 + i] = 0.f;
        return;
    }
    int e = (bid - 1)*256 + t;   // 0..12287
    unsigned short* OU = (unsigned short*)(ws + OFF_O);
    const double TWO_PI = 6.283185307179586476925286766559;
    if (e < 4096) {              // FdA[row=ri*16+ky][w]: re rows cos, im rows -sin
        int row = e >> 7, w = e & 127, ky = row & 15;
        double ang = TWO_PI * (double)((ky * w) & 127) / 128.0;
        double v = (row < 16) ? cos(ang) : -sin(ang);
        unsigned short hi, lo; split2((float)v, hi, lo);
        OU[e] = hi; OU[4096 + e] = lo;
    } else {                     // EdA[row=2kx+s][h]: s=0 cos, s=1 sin (of freq f(kx))
        int e2 = e - 4096, row = e2 >> 7, h = e2 & 127;
        int kx = row >> 1, f = kx < 16 ? kx : 96 + kx;
        double ang = TWO_PI * (double)((f * h) & 127) / 128.0;
        double v = (row & 1) ? sin(ang) : cos(ang);
        unsigned short hi, lo; split2((float)v, hi, lo);
        OU[8192 + e2] = hi; OU[16384 + e2] = lo;
    }
}

// weight transpose: [i][o][kx][ky] (x4 arrays) -> WT[mode][i][o][{re,im}]. grid (64=i, 2=part)
__global__ void k_trans(const float* __restrict__ w1r, const float* __restrict__ w1i,
                        const float* __restrict__ w2r, const float* __restrict__ w2i,
                        float* __restrict__ ws) {
    __shared__ float Lr[16*257], Li[16*257];
    int t = threadIdx.x;
    int i = blockIdx.x;
    int part = blockIdx.y;
    float* WT = ws + OFF_WT;
    const float* wr = part ? w2r : w1r;
    const float* wi = part ? w2i : w1i;
    for (int oc = 0; oc < 4; oc++) {
        int o0 = oc * 16;
        __syncthreads();
        for (int idx = t; idx < 4096; idx += 256) {
            int oo = idx >> 8, m = idx & 255;
            Lr[oo*257 + m] = wr[(i*64 + o0 + oo)*256 + m];
            Li[oo*257 + m] = wi[(i*64 + o0 + oo)*256 + m];
        }
        __syncthreads();
        for (int idx = t; idx < 8192; idx += 256) {
            int mode = idx >> 5, rem = idx & 31, oo = rem >> 1, ri = rem & 1;
            float val = ri ? Li[oo*257 + mode] : Lr[oo*257 + mode];
            int gm = part*256 + mode;
            WT[((gm*64 + i)*64 + (o0 + oo))*2 + ri] = val;
        }
    }
}

// bf16-split MLP weights + iDFT-w matrix M into the dead X region. grid 80
__global__ void k_wmlp(const float* __restrict__ mw1, const float* __restrict__ mw2,
                       float* __restrict__ ws) {
    int i = blockIdx.x * 256 + threadIdx.x;   // [0, 20480)
    unsigned short* xu = (unsigned short*)(ws + OFF_X);
    if (i < 8192) {
        unsigned short hi, lo; split2(mw1[i], hi, lo);
        xu[i] = hi; xu[8192 + i] = lo;
    } else if (i < 16384) {
        int k = i - 8192;
        unsigned short hi, lo; split2(mw2[k], hi, lo);
        xu[16384 + k] = hi; xu[24576 + k] = lo;
    } else if (i < 20480) {
        int m = i - 16384;           // w*32 + k
        int w = m >> 5, k = m & 31;
        int ky = k >> 1;
        double ang = 6.283185307179586476925286766559 * (double)((ky * w) & 127) / 128.0;
        double v = (k & 1) ? -sin(ang) : cos(ang);
        double a = (ky == 0) ? 1.0 : 2.0;
        float val = (float)(v * a) * (1.f/16384.f);
        unsigned short hi, lo; split2(val, hi, lo);
        xu[32768 + m] = hi; xu[36864 + m] = lo;
    }
}

// MFMA forward DFT along w on RAW x, sector-dense reads, c split across 2 blocks
// for occupancy (grid 1024 = 4 blocks/CU). grid (hq=32, cs=2, b=16): block =
// 4 h (wave wv owns h = hq*4+wv) x 32 c (c0 = cs*32). Instance-norm-1 stats
// folded into staging. Wave-private staging; barrier only before PT write.
// Output PT[b][(ky*64+c)*2+ri][h] u32-packed bf16 hi/lo (layout unchanged).
__global__ __launch_bounds__(256) void k_dftw(const float* __restrict__ x, float* __restrict__ ws) {
    __shared__ unsigned BTall[4096];    // 16KB: per-wave 4KB {BTh 2KB | BTl 2KB}; reused as trans
    int t = threadIdx.x;
    int hq = blockIdx.x, cs = blockIdx.y, b = blockIdx.z;
    int c0 = cs*32;
    int l = t & 63, wv = t >> 6;
    int h = hq*4 + wv;
    char* wbase = (char*)BTall + wv*4096;

    const unsigned short* OU = (const unsigned short*)(ws + OFF_O);
    const unsigned short* FdAh = OU, *FdAl = OU + 4096;

    // A-frags: FdA rows (mt*16 + lane&15), k = kc*32 + oct*8
    bfrag ma_h[2][4], ma_l[2][4];
    #pragma unroll
    for (int mt = 0; mt < 2; mt++)
        #pragma unroll
        for (int kc = 0; kc < 4; kc++) {
            int off = (mt*16 + (l & 15))*128 + kc*32 + (l >> 4)*8;
            ma_h[mt][kc] = *(const bfrag*)(FdAh + off);
            ma_l[mt][kc] = *(const bfrag*)(FdAl + off);
        }
    f4v acc[2][2];
    #pragma unroll
    for (int mt = 0; mt < 2; mt++)
        #pragma unroll
        for (int nt = 0; nt < 2; nt++) acc[mt][nt] = (f4v){0.f,0.f,0.f,0.f};

    float s1a[4] = {0,0,0,0}, s2a[4] = {0,0,0,0};   // stats for c = c0 + 4*cq + j
    int cq = l & 7, r = l >> 3;
    const float* xb = x + ((long)(b*128 + h))*8192 + c0;  // this wave's h row, c half

    #pragma unroll
    for (int kc = 0; kc < 4; kc++) {
        // ---- stage (dense): 8-lane groups read 128B contiguous (2 full sectors) ----
        #pragma unroll
        for (int it = 0; it < 2; it++) {
            int wp = it*8 + r;                       // w-pair 0..15
            const float* src = xb + (kc*32 + wp*2)*64 + cq*4;
            float4 a = *(const float4*)src;
            float4 bb = *(const float4*)(src + 64);
            #pragma unroll
            for (int j = 0; j < 4; j++) {
                float va = F4GET(a, j), vb = F4GET(bb, j);
                s1a[j] += va + vb;
                s2a[j] += va*va + vb*vb;
                unsigned short ah, al2, bh2, bl2;
                split2(va, ah, al2); split2(vb, bh2, bl2);
                unsigned hp = (unsigned)ah | ((unsigned)bh2 << 16);
                unsigned lp = (unsigned)al2 | ((unsigned)bl2 << 16);
                int lc = cq + 8*j;                   // col index 0..31
                unsigned bad = (unsigned)(lc*64 + ((wp*4) ^ (((lc >> 1) & 3) << 4)));
                *(unsigned*)(wbase + bad) = hp;
                *(unsigned*)(wbase + 2048 + bad) = lp;
            }
        }
        // ---- MFMA: 2 Ntiles x 2 Mtiles, 3-term hi/lo ----
        #pragma unroll
        for (int nt = 0; nt < 2; nt++) {
            int lc = nt*16 + (l & 15);
            unsigned ro = (unsigned)(lc*64 + (((l >> 4)*16) ^ (((lc >> 1) & 3) << 4)));
            bfrag bh = *(const bfrag*)(wbase + ro);
            bfrag bl = *(const bfrag*)(wbase + 2048 + ro);
            #pragma unroll
            for (int mt = 0; mt < 2; mt++) {
                f4v a_ = acc[mt][nt];
                a_ = MFMA(ma_h[mt][kc], bh, a_);
                a_ = MFMA(ma_h[mt][kc], bl, a_);
                a_ = MFMA(ma_l[mt][kc], bh, a_);
                acc[mt][nt] = a_;
            }
        }
    }
    // ---- stats reduce (over r-groups sharing cq) + atomics ----
    #pragma unroll
    for (int j = 0; j < 4; j++) {
        s1a[j] += __shfl_down(s1a[j], 8, 64);
        s1a[j] += __shfl_down(s1a[j], 16, 64);
        s1a[j] += __shfl_down(s1a[j], 32, 64);
        s2a[j] += __shfl_down(s2a[j], 8, 64);
        s2a[j] += __shfl_down(s2a[j], 16, 64);
        s2a[j] += __shfl_down(s2a[j], 32, 64);
    }
    if (l < 8) {
        #pragma unroll
        for (int j = 0; j < 4; j++) {
            int c = c0 + 4*cq + j;
            atomicAdd(&ws[OFF_S1 + (b*64 + c)*2],     s1a[j]);
            atomicAdd(&ws[OFF_S1 + (b*64 + c)*2 + 1], s2a[j]);
        }
    }
    // ---- epilogue: split-pack -> wave trans buf [trow=ri*16+ky][c_local 32] u32 ----
    #pragma unroll
    for (int mt = 0; mt < 2; mt++)
        #pragma unroll
        for (int nt = 0; nt < 2; nt++)
            #pragma unroll
            for (int rr = 0; rr < 4; rr++) {
                float v = acc[mt][nt][rr];
                unsigned short hi, lo; split2(v, hi, lo);
                int trow = mt*16 + (l >> 4)*4 + rr;
                // invert staging col permutation: lc = nt*16+(l&15) -> c_local = (lc&7)*4 + (lc>>3)
                int c_local = (l & 7)*4 + nt*2 + ((l >> 3) & 1);
                unsigned ad = (unsigned)(trow*128 + ((c_local*4) ^ ((trow & 7) << 4)));
                *(unsigned*)(wbase + ad) = ((unsigned)hi << 16) | (unsigned)lo;
            }
    __syncthreads();
    // ---- cross-wave gather: uint4 = 4 h values -> PT row segment ----
    unsigned* PT = (unsigned*)(ws + OFF_PQ);
    #pragma unroll
    for (int s = 0; s < 4; s++) {
        int seg = s*256 + t;                 // 1024 (trow,c) pairs
        int trow = seg >> 5, c = seg & 31;
        unsigned ad = (unsigned)(trow*128 + ((c*4) ^ ((trow & 7) << 4)));
        uint4 vz;
        vz.x = *(const unsigned*)((const char*)BTall + ad);
        vz.y = *(const unsigned*)((const char*)BTall + 4096 + ad);
        vz.z = *(const unsigned*)((const char*)BTall + 8192 + ad);
        vz.w = *(const unsigned*)((const char*)BTall + 12288 + ad);
        int ri = trow >> 4, ky = trow & 15;
        long grow = ((long)(ky*64 + c0 + c))*2 + ri;
        *(uint4*)(PT + (((long)b*2048 + grow) << 7) + hq*4) = vz;
    }
}

// MFMA forward DFT along h: X[2kx+s][(c,ri)] = EdA @ PT (per ky,b).
// Complex combine: Xr = G[2kx][colr]+G[2kx+1][coli], Xi = G[2kx][coli]-G[2kx+1][colr]
// via shfl_xor(1). grid (ky=16, b=16); wave wv = Mtile wv. X stays f32 legacy layout.
__global__ __launch_bounds__(256) void k_dfth(float* __restrict__ ws) {
    __shared__ unsigned Bsh[16384];   // BTh 32KB (128 cols x 256B) | BTl 32KB
    int t = threadIdx.x;
    int ky = blockIdx.x, b = blockIdx.y;
    int l = t & 63, wv = t >> 6;
    char* bh_base = (char*)Bsh;
    char* bl_base = bh_base + 32768;
    const unsigned* PT = (const unsigned*)(ws + OFF_PQ);
    const unsigned short* OU = (const unsigned short*)(ws + OFF_O);
    const unsigned short* EdAh = OU + 8192, *EdAl = OU + 16384;

    // ---- stage PT rows (col n = c*2+ri of this ky) -> BT[n][128 kk] hi/lo ----
    {
        int n = t >> 1, hh = (t & 1)*64;
        const uint4* src = (const uint4*)(PT + ((long)b*2048 + ky*128 + n)*128 + hh);
        #pragma unroll
        for (int jj = 0; jj < 16; jj++) {
            uint4 v = src[jj];
            unsigned h01 = (v.x >> 16) | (v.y & 0xFFFF0000u);
            unsigned h23 = (v.z >> 16) | (v.w & 0xFFFF0000u);
            unsigned l01 = (v.x & 0xFFFFu) | (v.y << 16);
            unsigned l23 = (v.z & 0xFFFFu) | (v.w << 16);
            int kk = hh + jj*4;
            unsigned ad = (unsigned)(n*256 + ((kk*2) ^ ((n & 7) << 4)));
            *(uint2*)(bh_base + ad) = make_uint2(h01, h23);
            *(uint2*)(bl_base + ad) = make_uint2(l01, l23);
        }
    }
    // A-frags for this wave's Mtile
    bfrag ea_h[4], ea_l[4];
    #pragma unroll
    for (int kc = 0; kc < 4; kc++) {
        int off = (wv*16 + (l & 15))*128 + kc*32 + (l >> 4)*8;
        ea_h[kc] = *(const bfrag*)(EdAh + off);
        ea_l[kc] = *(const bfrag*)(EdAl + off);
    }
    __syncthreads();
    f4v acc[8];
    #pragma unroll
    for (int nt = 0; nt < 8; nt++) acc[nt] = (f4v){0.f,0.f,0.f,0.f};
    #pragma unroll
    for (int kc = 0; kc < 4; kc++)
        #pragma unroll
        for (int nt = 0; nt < 8; nt++) {
            int col = nt*16 + (l & 15);
            unsigned ro = (unsigned)(col*256 + ((kc*64 + (l >> 4)*16) ^ ((col & 7) << 4)));
            bfrag bh = *(const bfrag*)(bh_base + ro);
            bfrag bl = *(const bfrag*)(bl_base + ro);
            acc[nt] = MFMA(ea_h[kc], bh, acc[nt]);
            acc[nt] = MFMA(ea_h[kc], bl, acc[nt]);
            acc[nt] = MFMA(ea_l[kc], bh, acc[nt]);
        }
    // ---- epilogue: complex combine + store X (f32, legacy layout) ----
    float* X = ws + OFF_X;
    #pragma unroll
    for (int nt = 0; nt < 8; nt++)
        #pragma unroll
        for (int p = 0; p < 2; p++) {
            float s0 = acc[nt][2*p], s1 = acc[nt][2*p + 1];
            float partner = __shfl_xor(s1, 1, 64);
            float res = (l & 1) ? (s0 - partner) : (s0 + partner);
            int kx = wv*8 + (l >> 4)*2 + p;
            X[(((long)b*32 + kx)*16 + ky)*128 + nt*16 + (l & 15)] = res;
        }
}

// per-mode complex mix with rho1 scaling folded into X staging. grid 512 (=mode)
__global__ void k_mix(float* __restrict__ ws) {
    __shared__ float Wsh[8192];
    __shared__ float Xs[2048];
    __shared__ float rhoT[1024];
    int t = threadIdx.x;
    int mode = blockIdx.x;
    int kxI = mode >> 4, ky = mode & 15;
    const float* WT = ws + OFF_WT;
    const float* X = ws + OFF_X;
    float* O = ws + OFF_O;
    for (int i = t; i < 1024; i += 256) {
        float a = ws[OFF_S1 + 2*i], s = ws[OFF_S1 + 2*i + 1];
        float m = a * (1.f/16384.f);
        float v = s * (1.f/16384.f) - m*m;
        rhoT[i] = rsqrtf(v + 1e-5f);
    }
    for (int idx = t; idx < 8192; idx += 256) Wsh[idx] = WT[(long)mode*8192 + idx];
    __syncthreads();
    for (int idx = t; idx < 2048; idx += 256) {
        int b = idx >> 7, r = idx & 127;
        Xs[idx] = X[((b*32 + kxI)*16 + ky)*128 + r] * rhoT[b*64 + (r >> 1)];
    }
    __syncthreads();
    int o = t & 63, bg = t >> 6;
    float accr[4] = {0,0,0,0}, acci[4] = {0,0,0,0};
    for (int i = 0; i < 64; i++) {
        float wr = Wsh[(i*64 + o)*2], wi = Wsh[(i*64 + o)*2 + 1];
        #pragma unroll
        for (int j = 0; j < 4; j++) {
            float xr = Xs[(bg*4 + j)*128 + 2*i], xi = Xs[(bg*4 + j)*128 + 2*i + 1];
            accr[j] += xr*wr - xi*wi;
            acci[j] += xr*wi + xi*wr;
        }
    }
    #pragma unroll
    for (int j = 0; j < 4; j++) {
        int b = bg*4 + j;
        float2* dst = (float2*)(O + ((b*32 + kxI)*16 + ky)*128);
        dst[o] = make_float2(accr[j], acci[j]);
    }
}

// Parseval stats of y directly from O. grid (16=b, 4=gg), 256 thr.
__global__ void k_pstats(float* __restrict__ ws) {
    __shared__ float red[256];
    int t = threadIdx.x, b = blockIdx.x, gg = blockIdx.y;
    int c = t & 63, g = t >> 6;
    const float* O = ws + OFF_O + (long)b*65536;   // [(kxI*16+ky)*128 + 2c]
    float t0 = 0.f, t2 = 0.f;
    int k0 = gg*8 + g*2;
    for (int kxI = k0; kxI < k0 + 2; kxI++)
        for (int ky = 0; ky < 16; ky++) {
            float re = O[(kxI*16 + ky)*128 + 2*c];
            float im = O[(kxI*16 + ky)*128 + 2*c + 1];
            float p = re*re + im*im;
            if (ky == 0) t0 += p; else t2 += p;
        }
    float s2p = 0.5f*t0 + 2.f*t2;
    if (gg == 0 && g == 0) {
        float ar = O[2*c], ai = O[2*c + 1];        // kxI=0, ky=0
        float t1 = ar*ar - ai*ai;
        for (int k = 1; k <= 15; k++) {
            float xr = O[(k*16)*128 + 2*c],        xi = O[(k*16)*128 + 2*c + 1];
            float yr = O[((32-k)*16)*128 + 2*c],   yi = O[((32-k)*16)*128 + 2*c + 1];
            t1 += 2.f*(xr*yr - xi*yi);
        }
        s2p += 0.5f*t1;
        ws[OFF_S2 + (b*64 + c)*2] = ar;            // s1 (mean term)
    }
    red[t] = s2p;
    __syncthreads();
    if (t < 64) {
        float s = red[t] + red[t+64] + red[t+128] + red[t+192];
        atomicAdd(&ws[OFF_S2 + (b*64 + t)*2 + 1], s * (1.f/16384.f));
    }
}

// inverse DFT along h: Q[b][h][ky][o] = sum_kx Out e^{+i 2pi f(kx) h/128}. grid (hg=16,b=16)
__global__ void k_idfth(float* __restrict__ ws) {
    __shared__ float Os[8192];
    __shared__ float tblL[256];
    int t = threadIdx.x;
    int hg = blockIdx.x, b = blockIdx.y;
    for (int i = t; i < 256; i += 256) tblL[i] = ws[OFF_TBL + i];
    const float* O = ws + OFF_O;
    float* Q = ws + OFF_PQ;
    int o = t & 63, kyg = t >> 6;
    float accr[4][8], acci[4][8];
    #pragma unroll
    for (int kk = 0; kk < 4; kk++)
        #pragma unroll
        for (int h = 0; h < 8; h++) { accr[kk][h] = 0.f; acci[kk][h] = 0.f; }
    for (int kc = 0; kc < 8; kc++) {
        __syncthreads();
        for (int idx = t; idx < 8192; idx += 256) Os[idx] = O[(long)b*65536 + kc*8192 + idx];
        __syncthreads();
        for (int k4 = 0; k4 < 4; k4++) {
            int kxI = kc*4 + k4;
            int freq = kxI < 16 ? kxI : 96 + kxI;
            float vr[4], vi[4];
            #pragma unroll
            for (int kk = 0; kk < 4; kk++) {
                int ky = kyg*4 + kk;
                vr[kk] = Os[((k4*16 + ky)*64 + o)*2];
                vi[kk] = Os[((k4*16 + ky)*64 + o)*2 + 1];
            }
            for (int h = 0; h < 8; h++) {
                int habs = hg*8 + h;
                int m = (freq * habs) & 127;
                float cs = tblL[2*m], sn = tblL[2*m + 1];
                #pragma unroll
                for (int kk = 0; kk < 4; kk++) {
                    accr[kk][h] += vr[kk]*cs - vi[kk]*sn;   // * e^{+i th}
                    acci[kk][h] += vr[kk]*sn + vi[kk]*cs;
                }
            }
        }
    }
    #pragma unroll
    for (int kk = 0; kk < 4; kk++)
        #pragma unroll
        for (int h = 0; h < 8; h++) {
            int ky = kyg*4 + kk, habs = hg*8 + h;
            float2* dst = (float2*)(Q + ((long)(b*128 + habs)*16 + ky)*128);
            dst[o] = make_float2(accr[kk][h], acci[kk][h]);
        }
}

// fused MFMA kernel: Y = M@Qm (iDFT-w), z = (Y-mu)*rho, h = GELU(z@W1+b1),
// out = h@W2+b2. G1 keeps hi/lo 3-MFMA (rho ~316 amplifies); z/W1/W2/h single bf16.
// zhS/hhS rows are wave-private -> only the post-staging barrier is needed.
// LDS 75.3KB -> 2 blocks/CU. grid (h=128,b=16)
__global__ __launch_bounds__(256, 2) void k_mlp(const float* __restrict__ mb1,
                      const float* __restrict__ mb2,
                      float* __restrict__ out, const float* __restrict__ ws) {
    __shared__ unsigned short zhS[8192];                // z[w][64c], swz (w&7)<<4
    __shared__ unsigned short w1hS[8192];               // w1[j][64c], swz (j&7)<<4
    __shared__ unsigned short w2hS[8192];               // w2[o][128j], swz (o&15)<<4
    __shared__ unsigned short hhS[8192];                // h-half [w][64jl], swz (w&7)<<4
    __shared__ unsigned short qhS[2560], qlS[2560];     // QmT[c][40k] hi/lo
    __shared__ float muL[64], rhoL[64], b1L[128], b2L[64];
    int t = threadIdx.x;
    int h = blockIdx.x, b = blockIdx.y;
    int l = t & 63, wv = t >> 6;

    const unsigned short* xu = (const unsigned short*)(ws + OFF_X);
    const unsigned short* w1hG = xu;
    const unsigned short* w2hG = xu + 16384;
    const unsigned short* MhG  = xu + 32768, *MlG  = xu + 36864;

    // ---- stage weights into LDS (XOR swizzle), hi parts only ----
    for (int ch = t; ch < 1024; ch += 256) {       // w1: rows j, stride 128B
        int j = ch >> 3, c0 = (ch & 7) * 8;
        unsigned off = (unsigned)(j*128 + c0*2) ^ (unsigned)((j & 7) << 4);
        *(bfrag*)((char*)w1hS + off) = *(const bfrag*)(w1hG + ch*8);
    }
    for (int ch = t; ch < 1024; ch += 256) {       // w2: rows o, stride 256B
        int o = ch >> 4, j0 = (ch & 15) * 8;
        unsigned off = (unsigned)(o*256 + j0*2) ^ (unsigned)((o & 15) << 4);
        *(bfrag*)((char*)w2hS + off) = *(const bfrag*)(w2hG + ch*8);
    }
    // ---- QmT[c][k] build; lane-consecutive k -> ~2-way banks ----
    const float* Qp = ws + OFF_PQ + (long)(b*128 + h)*2048;
    for (int i = t; i < 2048; i += 256) {
        int k = i & 31, c = i >> 5;
        float v = Qp[(k >> 1)*128 + c*2 + (k & 1)];
        unsigned short hi, lo; split2(v, hi, lo);
        qhS[c*40 + k] = hi; qlS[c*40 + k] = lo;
    }
    if (t < 64) {
        float s1 = ws[OFF_S2 + (b*64+t)*2], s2 = ws[OFF_S2 + (b*64+t)*2 + 1];
        float m = s1 * (1.f/16384.f);
        float v = s2 * (1.f/16384.f) - m*m;
        muL[t] = m; rhoL[t] = rsqrtf(v + 1e-5f);
        b2L[t] = mb2[t];
    }
    if (t >= 64 && t < 192) b1L[t - 64] = mb1[t - 64];
    // M A-frags from global (rows w of this wave's two 16-row tiles)
    bfrag ma_h[2], ma_l[2];
    #pragma unroll
    for (int q = 0; q < 2; q++) {
        int w = (wv + 4*q)*16 + (l & 15);
        ma_h[q] = *(const bfrag*)(MhG + w*32 + (l >> 4)*8);
        ma_l[q] = *(const bfrag*)(MlG + w*32 + (l >> 4)*8);
    }
    __syncthreads();   // cross-wave staging (w1/w2/q/biases) -- the ONLY barrier needed

    // ---- G1: Y = M @ Qm ; z = (Y - mu) * rho -> zhS (single bf16) ----
    #pragma unroll
    for (int q = 0; q < 2; q++) {
        int wt = wv + 4*q;
        #pragma unroll
        for (int ct = 0; ct < 4; ct++) {
            unsigned ro = (unsigned)((ct*16 + (l & 15))*80 + (l >> 4)*16);
            bfrag bh = *(const bfrag*)((const char*)qhS + ro);
            bfrag bl = *(const bfrag*)((const char*)qlS + ro);
            f4v acc = {0.f, 0.f, 0.f, 0.f};
            acc = MFMA(ma_h[q], bh, acc);
            acc = MFMA(ma_h[q], bl, acc);
            acc = MFMA(ma_l[q], bh, acc);
            int c = ct*16 + (l & 15);
            float mu_ = muL[c], rh_ = rhoL[c];
            #pragma unroll
            for (int r = 0; r < 4; r++) {
                int w = wt*16 + (l >> 4)*4 + r;
                float z = (acc[r] - mu_) * rh_;
                unsigned off = (unsigned)(w*128 + c*2) ^ (unsigned)((w & 7) << 4);
                *(unsigned short*)((char*)zhS + off) = f2bf_rn(z);
            }
        }
    }
    // (no barrier: zhS rows written above belong to THIS wave's tiles only)

    // cache z A-frags (single, reused for both j-halves)
    bfrag za[2][2];
    #pragma unroll
    for (int q = 0; q < 2; q++) {
        int w = (wv + 4*q)*16 + (l & 15);
        #pragma unroll
        for (int ks = 0; ks < 2; ks++) {
            unsigned off = (unsigned)(w*128 + (ks*32 + (l >> 4)*8)*2) ^ (unsigned)((w & 7) << 4);
            za[q][ks] = *(const bfrag*)((const char*)zhS + off);
        }
    }
    f4v accO[2][4];
    #pragma unroll
    for (int q = 0; q < 2; q++)
        #pragma unroll
        for (int ot = 0; ot < 4; ot++) accO[q][ot] = (f4v){0.f,0.f,0.f,0.f};

    #pragma unroll
    for (int jh = 0; jh < 2; jh++) {
        // ---- G2: h-half = GELU(z @ W1[:, jh*64 .. +64) + b1) ----
        #pragma unroll
        for (int q = 0; q < 2; q++) {
            int wt = wv + 4*q;
            #pragma unroll
            for (int jt = 0; jt < 4; jt++) {
                int j = jh*64 + jt*16 + (l & 15);
                f4v acc = {0.f, 0.f, 0.f, 0.f};
                #pragma unroll
                for (int ks = 0; ks < 2; ks++) {
                    unsigned off = (unsigned)(j*128 + (ks*32 + (l >> 4)*8)*2) ^ (unsigned)((j & 7) << 4);
                    bfrag bh = *(const bfrag*)((const char*)w1hS + off);
                    acc = MFMA(za[q][ks], bh, acc);
                }
                float bj = b1L[j];
                #pragma unroll
                for (int r = 0; r < 4; r++) {
                    int w = wt*16 + (l >> 4)*4 + r;
                    float hv = gelu_t(acc[r] + bj);
                    int jl = jt*16 + (l & 15);
                    unsigned off = (unsigned)(w*128 + jl*2) ^ (unsigned)((w & 7) << 4);
                    *(unsigned short*)((char*)hhS + off) = f2bf_rn(hv);
                }
            }
        }
        // (no barrier: hhS rows are wave-private)
        // ---- G3 partial: out += h-half @ W2[jh*64.., :] ----
        #pragma unroll
        for (int q = 0; q < 2; q++) {
            int w = (wv + 4*q)*16 + (l & 15);
            bfrag ha[2];
            #pragma unroll
            for (int ks = 0; ks < 2; ks++) {
                unsigned off = (unsigned)(w*128 + (ks*32 + (l >> 4)*8)*2) ^ (unsigned)((w & 7) << 4);
                ha[ks] = *(const bfrag*)((const char*)hhS + off);
            }
            #pragma unroll
            for (int ot = 0; ot < 4; ot++) {
                int o = ot*16 + (l & 15);
                f4v acc = accO[q][ot];
                #pragma unroll
                for (int ks = 0; ks < 2; ks++) {
                    int jj = jh*64 + ks*32 + (l >> 4)*8;
                    unsigned off = (unsigned)(o*256 + jj*2) ^ (unsigned)((o & 15) << 4);
                    bfrag bh = *(const bfrag*)((const char*)w2hS + off);
                    acc = MFMA(ha[ks], bh, acc);
                }
                accO[q][ot] = acc;
            }
        }
        // (no barrier: next jh writes only this wave's own hhS rows)
    }
    // ---- store out + b2 ----
    #pragma unroll
    for (int q = 0; q < 2; q++) {
        int wt = wv + 4*q;
        #pragma unroll
        for (int ot = 0; ot < 4; ot++) {
            int o = ot*16 + (l & 15);
            float bo = b2L[o];
            #pragma unroll
            for (int r = 0; r < 4; r++) {
                int w = wt*16 + (l >> 4)*4 + r;
                out[((long)(b*128 + h)*128 + w)*64 + o] = accO[q][ot][r] + bo;
            }
        }
    }
}

extern "C" void kernel_launch(void* const* d_in, const int* in_sizes, int n_in,
                              void* d_out, int out_size, void* d_ws, size_t ws_size,
                              hipStream_t stream) {
    const float* x   = (const float*)d_in[0];
    const float* w1r = (const float*)d_in[1];
    const float* w1i = (const float*)d_in[2];
    const float* w2r = (const float*)d_in[3];
    const float* w2i = (const float*)d_in[4];
    const float* mw1 = (const float*)d_in[5];
    const float* mb1 = (const float*)d_in[6];
    const float* mw2 = (const float*)d_in[7];
    const float* mb2 = (const float*)d_in[8];
    float* ws  = (float*)d_ws;
    float* out = (float*)d_out;

    k_init  <<<dim3(49),      dim3(256), 0, stream>>>(ws);
    k_trans <<<dim3(64,2),    dim3(256), 0, stream>>>(w1r, w1i, w2r, w2i, ws);
    k_dftw  <<<dim3(32,2,16), dim3(256), 0, stream>>>(x, ws);   // stats1 folded in
    k_dfth  <<<dim3(16,16),   dim3(256), 0, stream>>>(ws);
    k_mix   <<<dim3(512),     dim3(256), 0, stream>>>(ws);
    k_wmlp  <<<dim3(80),      dim3(256), 0, stream>>>(mw1, mw2, ws);  // X dead after k_mix
    k_pstats<<<dim3(16,4),    dim3(256), 0, stream>>>(ws);
    k_idfth <<<dim3(16,16),   dim3(256), 0, stream>>>(ws);
    k_mlp   <<<dim3(128,16),  dim3(256), 0, stream>>>(mb1, mb2, out, ws);
}